// Round 1
// baseline (2245.630 us; speedup 1.0000x reference)
//
#include <hip/hip_runtime.h>

#define B_ 4
#define S_ 2048
#define E_ 512
#define H_ 8
#define HD_ 64

// ---------------------------------------------------------------------------
// QKV projection: out = x @ W^T   (M=8192, N=512, K=512), fp32 LDS-tiled GEMM
// grid (128, 8, 3), block 256. z selects Wq/Wk/Wv.
// ---------------------------------------------------------------------------
__global__ __launch_bounds__(256) void qkv_gemm(
    const float* __restrict__ x, const float* __restrict__ Wq,
    const float* __restrict__ Wk, const float* __restrict__ Wv,
    float* __restrict__ qkv)
{
  const int z = blockIdx.z;
  const float* W = (z == 0) ? Wq : (z == 1) ? Wk : Wv;
  float* out = qkv + (size_t)z * (8192u * 512u);
  const int m0 = blockIdx.x * 64;
  const int n0 = blockIdx.y * 64;

  __shared__ __align__(16) float As[16][68];  // [k][m]
  __shared__ __align__(16) float Bs[16][68];  // [k][n]

  const int tid = threadIdx.x;
  const int tx = tid & 15, ty = tid >> 4;
  const int lrow = tid >> 2;           // 0..63
  const int lc4 = (tid & 3) << 2;      // 0,4,8,12

  float acc[4][4] = {};

  const float* Arow = x + (size_t)(m0 + lrow) * 512 + lc4;
  const float* Brow = W + (size_t)(n0 + lrow) * 512 + lc4;

  for (int k0 = 0; k0 < 512; k0 += 16) {
    float4 av = *(const float4*)(Arow + k0);
    float4 bv = *(const float4*)(Brow + k0);
    __syncthreads();
    As[lc4 + 0][lrow] = av.x;
    As[lc4 + 1][lrow] = av.y;
    As[lc4 + 2][lrow] = av.z;
    As[lc4 + 3][lrow] = av.w;
    Bs[lc4 + 0][lrow] = bv.x;
    Bs[lc4 + 1][lrow] = bv.y;
    Bs[lc4 + 2][lrow] = bv.z;
    Bs[lc4 + 3][lrow] = bv.w;
    __syncthreads();
#pragma unroll
    for (int kk = 0; kk < 16; ++kk) {
      float4 a4 = *(const float4*)&As[kk][ty * 4];
      float4 b4 = *(const float4*)&Bs[kk][tx * 4];
      acc[0][0] += a4.x * b4.x; acc[0][1] += a4.x * b4.y; acc[0][2] += a4.x * b4.z; acc[0][3] += a4.x * b4.w;
      acc[1][0] += a4.y * b4.x; acc[1][1] += a4.y * b4.y; acc[1][2] += a4.y * b4.z; acc[1][3] += a4.y * b4.w;
      acc[2][0] += a4.z * b4.x; acc[2][1] += a4.z * b4.y; acc[2][2] += a4.z * b4.z; acc[2][3] += a4.z * b4.w;
      acc[3][0] += a4.w * b4.x; acc[3][1] += a4.w * b4.y; acc[3][2] += a4.w * b4.z; acc[3][3] += a4.w * b4.w;
    }
  }
#pragma unroll
  for (int a = 0; a < 4; ++a) {
    float4 o = make_float4(acc[a][0], acc[a][1], acc[a][2], acc[a][3]);
    *(float4*)&out[(size_t)(m0 + ty * 4 + a) * 512 + n0 + tx * 4] = o;
  }
}

// ---------------------------------------------------------------------------
// Fused attention with relative skew, flash-style online softmax.
// BQ=64 (query tile), BT=32 (key tile). Block 256 threads.
// Thread micro-tile: rows i = i0 + ty*4 + a (a=0..3), score cols t = t0 + tx*2 + b
// (b=0..1); PV output cols d = tx*4 + dd.
//
// Srel[i,t]: d_rel = t-i;
//   d_rel <= 0 : q_i     . Er[S-1+d_rel]
//   d_rel == 1 : 0
//   d_rel >= 2 : q_{i+1} . Er[d_rel-2]
// Er slab per tile-pair indexed by li = (t-t0)-(i-i0)+63 in [0,94];
// global row g = (drel<=0 ? S-1+drel : drel-2), zero row iff g==-1.
// ---------------------------------------------------------------------------
#define ERT_STRIDE 100   // ert[d][li], 64 x 100 floats (also reused as ps[64][36])
#define PS_STRIDE  36

template <int MODE>
__device__ __forceinline__ void score_tile(
    const float (*__restrict__ qs)[68],
    const float (*__restrict__ kst)[36],
    const float* __restrict__ ertps,
    int tx, int ty, int Dfull, int Lb,
    float sc[4][2], float rl[4][2])
{
  const int qr = ty * 4;
#pragma unroll 2
  for (int d4 = 0; d4 < 16; ++d4) {
    const int d = d4 * 4;
    float4 q4[5];
#pragma unroll
    for (int r = 0; r < 5; ++r) q4[r] = *(const float4*)&qs[qr + r][d];
    float2 k2[4];
#pragma unroll
    for (int j = 0; j < 4; ++j) k2[j] = *(const float2*)&kst[d + j][tx * 2];
    float ev[4][5];
#pragma unroll
    for (int j = 0; j < 4; ++j)
#pragma unroll
      for (int e = 0; e < 5; ++e) ev[j][e] = ertps[(d + j) * ERT_STRIDE + Lb - 3 + e];
#pragma unroll
    for (int j = 0; j < 4; ++j) {
      float qsub[5];
#pragma unroll
      for (int r = 0; r < 5; ++r)
        qsub[r] = (j == 0) ? q4[r].x : (j == 1) ? q4[r].y : (j == 2) ? q4[r].z : q4[r].w;
      const float k0 = k2[j].x, k1 = k2[j].y;
#pragma unroll
      for (int a = 0; a < 4; ++a) {
        sc[a][0] += qsub[a] * k0;
        sc[a][1] += qsub[a] * k1;
        float qq0, qq1;
        if (MODE < 0)      { qq0 = qsub[a];     qq1 = qsub[a]; }
        else if (MODE > 0) { qq0 = qsub[a + 1]; qq1 = qsub[a + 1]; }
        else {
          qq0 = (Dfull + 0 - a > 0) ? qsub[a + 1] : qsub[a];
          qq1 = (Dfull + 1 - a > 0) ? qsub[a + 1] : qsub[a];
        }
        rl[a][0] += qq0 * ev[j][0 - a + 3];
        rl[a][1] += qq1 * ev[j][1 - a + 3];
      }
    }
  }
}

__global__ __launch_bounds__(256) void attn_kernel(
    const float* __restrict__ qkv, const float* __restrict__ Er,
    float* __restrict__ out)
{
  const int qb = blockIdx.x;       // 0..31 query tile
  const int bh = blockIdx.y;       // 0..31
  const int b = bh >> 3, h = bh & 7;
  const int i0 = qb * 64;
  const float scale = 0.04419417382415922f;   // 512^-0.5

  const float* q = qkv;
  const float* k = qkv + (size_t)8192 * 512;
  const float* v = qkv + (size_t)2 * 8192 * 512;

  __shared__ __align__(16) float qs[65][68];            // [i_local][d], row 64 = q_{i0+64}
  __shared__ __align__(16) float kst[64][36];           // [d][t_local]
  __shared__ __align__(16) float vs[32][68];            // [t_local][d]
  __shared__ __align__(16) float ertps[64 * ERT_STRIDE]; // ert[d][li]; reused as ps[i][t]

  const int tid = threadIdx.x;
  const int tx = tid & 15, ty = tid >> 4;

  const float* qbase = q + ((size_t)b * S_) * E_ + h * 64;
  const float* kbase = k + ((size_t)b * S_) * E_ + h * 64;
  const float* vbase = v + ((size_t)b * S_) * E_ + h * 64;

  // stage q tile: 65 rows x 64 d
  for (int idx = tid; idx < 65 * 16; idx += 256) {
    int r = idx >> 4, c4 = (idx & 15) << 2;
    int gi = i0 + r;
    float4 val = make_float4(0.f, 0.f, 0.f, 0.f);
    if (gi < S_) val = *(const float4*)&qbase[(size_t)gi * E_ + c4];
    *(float4*)&qs[r][c4] = val;
  }

  float m_r[4], l_r[4];
  float4 O4[4];
#pragma unroll
  for (int a = 0; a < 4; ++a) {
    m_r[a] = -1e30f; l_r[a] = 0.f;
    O4[a] = make_float4(0.f, 0.f, 0.f, 0.f);
  }

  const int Lb = 63 + 2 * tx - 4 * ty;  // er slab base col for this thread

  for (int tb = 0; tb < 64; ++tb) {
    const int t0 = tb * 32;
    const int dbase = t0 - i0;
    const int Dfull = dbase + 2 * tx - 4 * ty;

    __syncthreads();  // previous iteration fully consumed kst/vs/ertps

    // stage k (transposed) and v
    for (int idx = tid; idx < 32 * 16; idx += 256) {
      int r = idx >> 4, c4 = (idx & 15) << 2;   // r = t_local, c4 = d
      float4 kv4 = *(const float4*)&kbase[(size_t)(t0 + r) * E_ + c4];
      kst[c4 + 0][r] = kv4.x;
      kst[c4 + 1][r] = kv4.y;
      kst[c4 + 2][r] = kv4.z;
      kst[c4 + 3][r] = kv4.w;
      *(float4*)&vs[r][c4] = *(const float4*)&vbase[(size_t)(t0 + r) * E_ + c4];
    }
    // stage er slab transposed: 95 rows li in [0,94]
    for (int idx = tid; idx < 95 * 16; idx += 256) {
      int li = idx >> 4, c4 = (idx & 15) << 2;
      int drel = dbase + li - 63;
      int g = (drel <= 0) ? (S_ - 1 + drel) : (drel - 2);
      float4 ev = make_float4(0.f, 0.f, 0.f, 0.f);
      if (g >= 0) ev = *(const float4*)&Er[(size_t)g * HD_ + c4];
      ertps[(c4 + 0) * ERT_STRIDE + li] = ev.x;
      ertps[(c4 + 1) * ERT_STRIDE + li] = ev.y;
      ertps[(c4 + 2) * ERT_STRIDE + li] = ev.z;
      ertps[(c4 + 3) * ERT_STRIDE + li] = ev.w;
    }
    __syncthreads();

    float sc[4][2] = {};
    float rl[4][2] = {};
    if (dbase < 0)
      score_tile<-1>(qs, kst, ertps, tx, ty, Dfull, Lb, sc, rl);
    else if (dbase >= 64)
      score_tile<1>(qs, kst, ertps, tx, ty, Dfull, Lb, sc, rl);
    else
      score_tile<0>(qs, kst, ertps, tx, ty, Dfull, Lb, sc, rl);

    // online softmax (register + shuffle only)
    float p_[4][2];
    float alpha[4];
#pragma unroll
    for (int a = 0; a < 4; ++a) {
      float s0 = (sc[a][0] + rl[a][0]) * scale;
      float s1 = (sc[a][1] + rl[a][1]) * scale;
      float mt = fmaxf(s0, s1);
#pragma unroll
      for (int off = 1; off < 16; off <<= 1) mt = fmaxf(mt, __shfl_xor(mt, off, 64));
      float mnew = fmaxf(m_r[a], mt);
      float al = __expf(m_r[a] - mnew);
      float p0 = __expf(s0 - mnew);
      float p1 = __expf(s1 - mnew);
      float rs = p0 + p1;
#pragma unroll
      for (int off = 1; off < 16; off <<= 1) rs += __shfl_xor(rs, off, 64);
      l_r[a] = l_r[a] * al + rs;
      m_r[a] = mnew;
      alpha[a] = al;
      p_[a][0] = p0; p_[a][1] = p1;
    }

    __syncthreads();  // all ertps (Er slab) reads done before reuse as ps
#pragma unroll
    for (int a = 0; a < 4; ++a) {
      *(float2*)&ertps[(ty * 4 + a) * PS_STRIDE + tx * 2] = make_float2(p_[a][0], p_[a][1]);
      O4[a].x *= alpha[a]; O4[a].y *= alpha[a]; O4[a].z *= alpha[a]; O4[a].w *= alpha[a];
    }
    __syncthreads();  // ps visible

    // PV: O[i][d] += sum_t p[i][t] * v[t][d]
#pragma unroll
    for (int t4 = 0; t4 < 8; ++t4) {
      const int t = t4 * 4;
      float4 pr[4];
#pragma unroll
      for (int a = 0; a < 4; ++a)
        pr[a] = *(const float4*)&ertps[(ty * 4 + a) * PS_STRIDE + t];
      float4 vv[4];
#pragma unroll
      for (int j = 0; j < 4; ++j)
        vv[j] = *(const float4*)&vs[t + j][tx * 4];
#pragma unroll
      for (int a = 0; a < 4; ++a) {
        O4[a].x += pr[a].x * vv[0].x + pr[a].y * vv[1].x + pr[a].z * vv[2].x + pr[a].w * vv[3].x;
        O4[a].y += pr[a].x * vv[0].y + pr[a].y * vv[1].y + pr[a].z * vv[2].y + pr[a].w * vv[3].y;
        O4[a].z += pr[a].x * vv[0].z + pr[a].y * vv[1].z + pr[a].z * vv[2].z + pr[a].w * vv[3].z;
        O4[a].w += pr[a].x * vv[0].w + pr[a].y * vv[1].w + pr[a].z * vv[2].w + pr[a].w * vv[3].w;
      }
    }
  }

  // epilogue: out[b, i, h*64 + d] = O / l
  float* obase = out + ((size_t)b * S_ + i0) * E_ + h * 64;
#pragma unroll
  for (int a = 0; a < 4; ++a) {
    float inv = 1.f / l_r[a];
    float4 o = make_float4(O4[a].x * inv, O4[a].y * inv, O4[a].z * inv, O4[a].w * inv);
    *(float4*)&obase[(size_t)(ty * 4 + a) * E_ + tx * 4] = o;
  }
}

// ---------------------------------------------------------------------------
// In-place LayerNorm over E=512 per (b,s) row. grid 8192, block 256.
// ---------------------------------------------------------------------------
__global__ __launch_bounds__(256) void ln_kernel(
    float* __restrict__ io, const float* __restrict__ gamma,
    const float* __restrict__ beta)
{
  const int row = blockIdx.x;
  float* xr = io + (size_t)row * 512;
  const int tid = threadIdx.x;
  float2 v = *(const float2*)&xr[tid * 2];
  float s = v.x + v.y;
  float sq = v.x * v.x + v.y * v.y;
#pragma unroll
  for (int off = 1; off < 64; off <<= 1) {
    s += __shfl_xor(s, off, 64);
    sq += __shfl_xor(sq, off, 64);
  }
  __shared__ float red[8];
  const int wid = tid >> 6, lane = tid & 63;
  if (lane == 0) { red[wid] = s; red[wid + 4] = sq; }
  __syncthreads();
  s = red[0] + red[1] + red[2] + red[3];
  sq = red[4] + red[5] + red[6] + red[7];
  const float mean = s * (1.f / 512.f);
  float var = sq * (1.f / 512.f) - mean * mean;
  var = fmaxf(var, 0.f);
  const float rstd = rsqrtf(var + 1e-5f);
  float2 g = *(const float2*)&gamma[tid * 2];
  float2 be = *(const float2*)&beta[tid * 2];
  float2 o;
  o.x = (v.x - mean) * rstd * g.x + be.x;
  o.y = (v.y - mean) * rstd * g.y + be.y;
  *(float2*)&xr[tid * 2] = o;
}

extern "C" void kernel_launch(void* const* d_in, const int* in_sizes, int n_in,
                              void* d_out, int out_size, void* d_ws, size_t ws_size,
                              hipStream_t stream) {
  const float* x     = (const float*)d_in[0];
  const float* Wq    = (const float*)d_in[1];
  const float* Wk    = (const float*)d_in[2];
  const float* Wv    = (const float*)d_in[3];
  const float* Er    = (const float*)d_in[4];
  const float* gamma = (const float*)d_in[5];
  const float* beta  = (const float*)d_in[6];
  float* out = (float*)d_out;
  float* qkv = (float*)d_ws;   // 3 x 8192x512 fp32 = 48 MB scratch

  qkv_gemm<<<dim3(128, 8, 3), 256, 0, stream>>>(x, Wq, Wk, Wv, qkv);
  attn_kernel<<<dim3(32, 32), 256, 0, stream>>>(qkv, Er, out);
  ln_kernel<<<dim3(8192), 256, 0, stream>>>(out, gamma, beta);
}

// Round 2
// 455.164 us; speedup vs baseline: 4.9337x; 4.9337x over previous
//
#include <hip/hip_runtime.h>

#define B_ 4
#define S_ 2048
#define E_ 512
#define H_ 8
#define HD_ 64

typedef float f32x4 __attribute__((ext_vector_type(4)));
typedef __bf16 bf16x8 __attribute__((ext_vector_type(8)));

#define MFMA16(a, b, c) __builtin_amdgcn_mfma_f32_16x16x32_bf16((a), (b), (c), 0, 0, 0)

__device__ __forceinline__ unsigned short f2bf(float f) {
  union { float f; unsigned u; } x; x.f = f;
  unsigned r = (x.u + 0x7fffu + ((x.u >> 16) & 1u)) >> 16;
  return (unsigned short)r;
}
__device__ __forceinline__ float bf2f(unsigned short s) {
  union { unsigned u; float f; } x; x.u = ((unsigned)s) << 16;
  return x.f;
}

// ---------------------------------------------------------------------------
// QKV projection, bf16 MFMA: out[z] = bf16(x @ W[z]^T). M=8192,N=512,K=512.
// grid (64, 4, 3), block 256 (4 waves, 2x2 of 64x64 per wave).
// ---------------------------------------------------------------------------
__global__ __launch_bounds__(256) void qkv_gemm_mfma(
    const float* __restrict__ x, const float* __restrict__ Wq,
    const float* __restrict__ Wk, const float* __restrict__ Wv,
    unsigned short* __restrict__ qkvb)
{
  const int z = blockIdx.z;
  const float* W = (z == 0) ? Wq : (z == 1) ? Wk : Wv;
  unsigned short* out = qkvb + (size_t)z * (8192u * 512u);
  const int m0 = blockIdx.x * 128, n0 = blockIdx.y * 128;

  __shared__ __align__(16) unsigned short As[128 * 72];
  __shared__ __align__(16) unsigned short Bs[128 * 72];

  const int tid = threadIdx.x;
  const int w = tid >> 6, l = tid & 63, lm = l & 15, lq = l >> 4;
  const int wm = w & 1, wn = w >> 1;

  f32x4 acc[4][4];
#pragma unroll
  for (int a = 0; a < 4; ++a)
#pragma unroll
    for (int b = 0; b < 4; ++b) acc[a][b] = (f32x4){0.f, 0.f, 0.f, 0.f};

  for (int k0 = 0; k0 < 512; k0 += 64) {
    __syncthreads();
    for (int idx = tid; idx < 2048; idx += 256) {
      int r = idx >> 4, c4 = (idx & 15) * 4;
      float4 a = *(const float4*)&x[(size_t)(m0 + r) * 512 + k0 + c4];
      float4 bq = *(const float4*)&W[(size_t)(n0 + r) * 512 + k0 + c4];
      ushort4 av; av.x = f2bf(a.x); av.y = f2bf(a.y); av.z = f2bf(a.z); av.w = f2bf(a.w);
      ushort4 bv; bv.x = f2bf(bq.x); bv.y = f2bf(bq.y); bv.z = f2bf(bq.z); bv.w = f2bf(bq.w);
      *(ushort4*)&As[r * 72 + c4] = av;
      *(ushort4*)&Bs[r * 72 + c4] = bv;
    }
    __syncthreads();
#pragma unroll
    for (int ka = 0; ka < 2; ++ka) {
      bf16x8 af[4];
#pragma unroll
      for (int mt = 0; mt < 4; ++mt)
        af[mt] = *(const bf16x8*)&As[(wm * 64 + mt * 16 + lm) * 72 + ka * 32 + lq * 8];
#pragma unroll
      for (int nt = 0; nt < 4; ++nt) {
        bf16x8 bfv = *(const bf16x8*)&Bs[(wn * 64 + nt * 16 + lm) * 72 + ka * 32 + lq * 8];
#pragma unroll
        for (int mt = 0; mt < 4; ++mt) acc[mt][nt] = MFMA16(af[mt], bfv, acc[mt][nt]);
      }
    }
  }
#pragma unroll
  for (int mt = 0; mt < 4; ++mt)
#pragma unroll
    for (int nt = 0; nt < 4; ++nt)
#pragma unroll
      for (int reg = 0; reg < 4; ++reg)
        out[(size_t)(m0 + wm * 64 + mt * 16 + lq * 4 + reg) * 512 +
            n0 + wn * 64 + nt * 16 + lm] = f2bf(acc[mt][nt][reg]);
}

// ---------------------------------------------------------------------------
// V transpose: vt[b][hd][s] = v[b][s][hd] (bf16). grid (32, 8, 4), block 256.
// ---------------------------------------------------------------------------
__global__ __launch_bounds__(256) void v_transpose(
    const unsigned short* __restrict__ v, unsigned short* __restrict__ vt)
{
  const int s0 = blockIdx.x * 64, c0 = blockIdx.y * 64, b = blockIdx.z;
  __shared__ __align__(16) unsigned short T[64 * 72];
  const int tid = threadIdx.x;
  for (int idx = tid; idx < 512; idx += 256) {
    int r = idx >> 3, c8 = (idx & 7) * 8;
    *(uint4*)&T[r * 72 + c8] =
        *(const uint4*)&v[(size_t)(b * 2048 + s0 + r) * 512 + c0 + c8];
  }
  __syncthreads();
  for (int idx = tid; idx < 512; idx += 256) {
    int d = idx >> 3, s8 = (idx & 7) * 8;
    union { unsigned short u[8]; uint4 q; } tmp;
#pragma unroll
    for (int j = 0; j < 8; ++j) tmp.u[j] = T[(s8 + j) * 72 + d];
    *(uint4*)&vt[((size_t)(b * 512) + c0 + d) * 2048 + s0 + s8] = tmp.q;
  }
}

// ---------------------------------------------------------------------------
// Er fp32 -> bf16. grid 128 x 256, 4 elems/thread. 2048*64 = 131072 elems.
// ---------------------------------------------------------------------------
__global__ __launch_bounds__(256) void er_convert(
    const float* __restrict__ er, unsigned short* __restrict__ erb)
{
  int i = (blockIdx.x * 256 + threadIdx.x) * 4;
  float4 f = *(const float4*)&er[i];
  ushort4 o; o.x = f2bf(f.x); o.y = f2bf(f.y); o.z = f2bf(f.z); o.w = f2bf(f.w);
  *(ushort4*)&erb[i] = o;
}

// ---------------------------------------------------------------------------
// Fused attention with relative skew, MFMA + flash-style online softmax.
// BQ=64 q-rows, BT=64 keys/iter. Block 256 = 4 waves; wave w owns q-rows
// [i0+16w, i0+16w+16).
//
// Skew (verified vs reference algebra): drel = t - i;
//   drel <= 0 : q_i . Er[2047+drel] ;  drel == 1 : 0 ;  drel >= 2 : q_{i+1} . Er[drel-2]
// Per k-tile, slab li = 63 + (t-t0) - (i-i0) in [0,126]; Rext[r][li] = q_{i0+r}.ErSlab[li]
// computed by MFMA (rows 0..64), gathered as Rx[i_l + (drel>=2)][li].
// ---------------------------------------------------------------------------
__global__ __launch_bounds__(256, 2) void attn_mfma(
    const unsigned short* __restrict__ qw, const unsigned short* __restrict__ kw,
    const unsigned short* __restrict__ vt, const unsigned short* __restrict__ erb,
    float* __restrict__ out)
{
  const int qb = blockIdx.x, bh = blockIdx.y;
  const int b = bh >> 3, h = bh & 7;
  const int i0 = qb * 64;
  const float scale = 0.04419417382415922f;  // 512^-0.5

  __shared__ __align__(16) unsigned short Qs[65 * 72];   // q rows i0..i0+64 [row][d]
  __shared__ __align__(16) unsigned short Ks[64 * 72];   // [t][d]
  __shared__ __align__(16) unsigned short VTs[64 * 72];  // [d][t]
  __shared__ __align__(16) unsigned short ErP[128 * 72]; // Er slab [li][d]; reused as P[i][t]
  __shared__ __align__(16) unsigned short Rx[65 * 130];  // Rext bf16 [isel][li]

  const int tid = threadIdx.x;
  const int w = tid >> 6, l = tid & 63, lm = l & 15, lq = l >> 4;

  const unsigned short* qbase = qw + ((size_t)(b * 2048)) * 512 + h * 64;
  const unsigned short* kbase = kw + ((size_t)(b * 2048)) * 512 + h * 64;
  const unsigned short* vtb = vt + ((size_t)(b * 512 + h * 64)) * 2048;

  // stage Q (65 rows x 64 d, bf16 copy)
  for (int idx = tid; idx < 65 * 8; idx += 256) {
    int r = idx >> 3, c8 = (idx & 7) * 8;
    int gi = i0 + r;
    uint4 val = make_uint4(0, 0, 0, 0);
    if (gi < 2048) val = *(const uint4*)&qbase[(size_t)gi * 512 + c8];
    *(uint4*)&Qs[r * 72 + c8] = val;
  }

  float m_r[4], l_r[4], alpha[4];
  f32x4 O[4];
#pragma unroll
  for (int a = 0; a < 4; ++a) {
    m_r[a] = -1e30f; l_r[a] = 0.f;
    O[a] = (f32x4){0.f, 0.f, 0.f, 0.f};
  }

  for (int tb = 0; tb < 32; ++tb) {
    const int t0 = tb * 64, dbase = t0 - i0;
    __syncthreads();  // prior iter fully consumed Ks/VTs/ErP (and P)

    // stage K and V^T tiles (bf16 copies)
    for (int idx = tid; idx < 512; idx += 256) {
      int r = idx >> 3, c8 = (idx & 7) * 8;
      *(uint4*)&Ks[r * 72 + c8] = *(const uint4*)&kbase[(size_t)(t0 + r) * 512 + c8];
      *(uint4*)&VTs[r * 72 + c8] = *(const uint4*)&vtb[(size_t)r * 2048 + t0 + c8];
    }
    // stage Er slab (li 0..127; li=127 is MFMA padding, never gathered)
    for (int idx = tid; idx < 1024; idx += 256) {
      int li = idx >> 3, c8 = (idx & 7) * 8;
      int drel = dbase + li - 63;
      uint4 ev = make_uint4(0, 0, 0, 0);
      if (drel != 1) {
        int g = (drel <= 0) ? (2047 + drel) : (drel - 2);
        ev = *(const uint4*)&erb[(size_t)g * 64 + c8];
      }
      *(uint4*)&ErP[li * 72 + c8] = ev;
    }
    __syncthreads();

    // ---- QK^T: wave's 16 rows x 64 cols ----
    f32x4 sc[4];
#pragma unroll
    for (int nt = 0; nt < 4; ++nt) sc[nt] = (f32x4){0.f, 0.f, 0.f, 0.f};
#pragma unroll
    for (int ka = 0; ka < 2; ++ka) {
      bf16x8 aq = *(const bf16x8*)&Qs[(w * 16 + lm) * 72 + ka * 32 + lq * 8];
#pragma unroll
      for (int nt = 0; nt < 4; ++nt) {
        bf16x8 bk = *(const bf16x8*)&Ks[(nt * 16 + lm) * 72 + ka * 32 + lq * 8];
        sc[nt] = MFMA16(aq, bk, sc[nt]);
      }
    }

    // ---- Rslab: wave w computes col-tiles {2w, 2w+1} x row-tiles 0..4 ----
    f32x4 rc[2][5];
#pragma unroll
    for (int c2 = 0; c2 < 2; ++c2)
#pragma unroll
      for (int rt = 0; rt < 5; ++rt) rc[c2][rt] = (f32x4){0.f, 0.f, 0.f, 0.f};
#pragma unroll
    for (int ka = 0; ka < 2; ++ka) {
      bf16x8 aq[5];
#pragma unroll
      for (int rt = 0; rt < 5; ++rt) {
        int row = rt * 16 + lm; if (row > 64) row = 64;  // rows >64 are dead padding
        aq[rt] = *(const bf16x8*)&Qs[row * 72 + ka * 32 + lq * 8];
      }
#pragma unroll
      for (int c2 = 0; c2 < 2; ++c2) {
        bf16x8 be = *(const bf16x8*)&ErP[((w * 2 + c2) * 16 + lm) * 72 + ka * 32 + lq * 8];
#pragma unroll
        for (int rt = 0; rt < 5; ++rt) rc[c2][rt] = MFMA16(aq[rt], be, rc[c2][rt]);
      }
    }
#pragma unroll
    for (int c2 = 0; c2 < 2; ++c2)
#pragma unroll
      for (int rt = 0; rt < 5; ++rt) {
        int colb = (w * 2 + c2) * 16 + lm;
#pragma unroll
        for (int reg = 0; reg < 4; ++reg) {
          int row = rt * 16 + lq * 4 + reg;
          if (row <= 64) Rx[row * 130 + colb] = f2bf(rc[c2][rt][reg]);
        }
      }
    __syncthreads();  // Rx complete; ErP (slab) dead

    // ---- gather skew + online softmax ----
    float p[4][4];  // [nt][reg]
#pragma unroll
    for (int reg = 0; reg < 4; ++reg) {
      const int i_l = w * 16 + lq * 4 + reg;
      float sv[4];
      float mx = -1e30f;
#pragma unroll
      for (int nt = 0; nt < 4; ++nt) {
        int t_l = nt * 16 + lm;
        int dr = dbase + t_l - i_l;
        int li = 63 + t_l - i_l;
        int isel = i_l + (dr >= 2 ? 1 : 0);
        float rel = (dr == 1) ? 0.f : bf2f(Rx[isel * 130 + li]);
        float s = (sc[nt][reg] + rel) * scale;
        sv[nt] = s;
        mx = fmaxf(mx, s);
      }
#pragma unroll
      for (int off = 1; off < 16; off <<= 1) mx = fmaxf(mx, __shfl_xor(mx, off, 64));
      float mnew = fmaxf(m_r[reg], mx);
      float al = __expf(m_r[reg] - mnew);
      float rs = 0.f;
#pragma unroll
      for (int nt = 0; nt < 4; ++nt) {
        float pv = __expf(sv[nt] - mnew);
        p[nt][reg] = pv;
        rs += pv;
      }
#pragma unroll
      for (int off = 1; off < 16; off <<= 1) rs += __shfl_xor(rs, off, 64);
      l_r[reg] = l_r[reg] * al + rs;
      m_r[reg] = mnew;
      alpha[reg] = al;
    }
    // write P (bf16) into ErP region; rescale O
#pragma unroll
    for (int nt = 0; nt < 4; ++nt) {
#pragma unroll
      for (int reg = 0; reg < 4; ++reg)
        ErP[(w * 16 + lq * 4 + reg) * 72 + nt * 16 + lm] = f2bf(p[nt][reg]);
    }
#pragma unroll
    for (int nt = 0; nt < 4; ++nt)
#pragma unroll
      for (int reg = 0; reg < 4; ++reg) O[nt][reg] *= alpha[reg];
    __syncthreads();  // P visible

    // ---- PV ----
#pragma unroll
    for (int ka = 0; ka < 2; ++ka) {
      bf16x8 ap = *(const bf16x8*)&ErP[(w * 16 + lm) * 72 + ka * 32 + lq * 8];
#pragma unroll
      for (int nt = 0; nt < 4; ++nt) {
        bf16x8 bv = *(const bf16x8*)&VTs[(nt * 16 + lm) * 72 + ka * 32 + lq * 8];
        O[nt] = MFMA16(ap, bv, O[nt]);
      }
    }
  }

  // epilogue: out fp32
  float* ob = out + ((size_t)(b * 2048) + i0) * 512 + h * 64;
#pragma unroll
  for (int reg = 0; reg < 4; ++reg) {
    float inv = 1.f / l_r[reg];
    int i_l = w * 16 + lq * 4 + reg;
#pragma unroll
    for (int nt = 0; nt < 4; ++nt)
      ob[(size_t)i_l * 512 + nt * 16 + lm] = O[nt][reg] * inv;
  }
}

// ---------------------------------------------------------------------------
// In-place LayerNorm over E=512 per (b,s) row. grid 8192, block 256.
// ---------------------------------------------------------------------------
__global__ __launch_bounds__(256) void ln_kernel(
    float* __restrict__ io, const float* __restrict__ gamma,
    const float* __restrict__ beta)
{
  const int row = blockIdx.x;
  float* xr = io + (size_t)row * 512;
  const int tid = threadIdx.x;
  float2 v = *(const float2*)&xr[tid * 2];
  float s = v.x + v.y;
  float sq = v.x * v.x + v.y * v.y;
#pragma unroll
  for (int off = 1; off < 64; off <<= 1) {
    s += __shfl_xor(s, off, 64);
    sq += __shfl_xor(sq, off, 64);
  }
  __shared__ float red[8];
  const int wid = tid >> 6, lane = tid & 63;
  if (lane == 0) { red[wid] = s; red[wid + 4] = sq; }
  __syncthreads();
  s = red[0] + red[1] + red[2] + red[3];
  sq = red[4] + red[5] + red[6] + red[7];
  const float mean = s * (1.f / 512.f);
  float var = sq * (1.f / 512.f) - mean * mean;
  var = fmaxf(var, 0.f);
  const float rstd = rsqrtf(var + 1e-5f);
  float2 g = *(const float2*)&gamma[tid * 2];
  float2 be = *(const float2*)&beta[tid * 2];
  float2 o;
  o.x = (v.x - mean) * rstd * g.x + be.x;
  o.y = (v.y - mean) * rstd * g.y + be.y;
  *(float2*)&xr[tid * 2] = o;
}

extern "C" void kernel_launch(void* const* d_in, const int* in_sizes, int n_in,
                              void* d_out, int out_size, void* d_ws, size_t ws_size,
                              hipStream_t stream) {
  const float* x     = (const float*)d_in[0];
  const float* Wq    = (const float*)d_in[1];
  const float* Wk    = (const float*)d_in[2];
  const float* Wv    = (const float*)d_in[3];
  const float* Er    = (const float*)d_in[4];
  const float* gamma = (const float*)d_in[5];
  const float* beta  = (const float*)d_in[6];
  float* out = (float*)d_out;

  // ws layout (bf16 shorts): qkv 3*8192*512, vT 4*512*2048, erb 2048*64  (~32.3 MB)
  unsigned short* qkvb = (unsigned short*)d_ws;
  unsigned short* vtb  = qkvb + (size_t)3 * 8192 * 512;
  unsigned short* erb  = vtb + (size_t)4 * 512 * 2048;
  unsigned short* vb   = qkvb + (size_t)2 * 8192 * 512;

  qkv_gemm_mfma<<<dim3(64, 4, 3), 256, 0, stream>>>(x, Wq, Wk, Wv, qkvb);
  er_convert<<<dim3(128), 256, 0, stream>>>(Er, erb);
  v_transpose<<<dim3(32, 8, 4), 256, 0, stream>>>(vb, vtb);
  attn_mfma<<<dim3(32, 32), 256, 0, stream>>>(qkvb, qkvb + (size_t)8192 * 512, vtb, erb, out);
  ln_kernel<<<dim3(8192), 256, 0, stream>>>(out, gamma, beta);
}